// Round 9
// baseline (380.068 us; speedup 1.0000x reference)
//
#include <hip/hip_runtime.h>
#include <hip/hip_bf16.h>

// CognitiveWorkspace — 3-dispatch decomposition (each separately profiled).
//   K_copy : flat float4 copy S -> outS (pure-copy BW probe, no branches)
//   K_gate : gate = sigmoid([H*Wq^T, mean_tag]*Wg^T+bg) (bf16 MFMA);
//            overwrites out hub cols with S*g + w_hub_shared; writes gate_out
//   K_fixup: overwrites spoke/hub_priv/tag cols with S + w
// Stream-ordered; no kernel reads d_out => replay-deterministic.

#define DM 2048      // d_model
#define DSZ 6656     // D_S
#define HUBOFF 4608  // hub_shared offset (floats)
#define TAGOFF 5120
#define NTOK 16384   // B*T
#define DHS 512      // d_hub_shared

typedef __attribute__((ext_vector_type(8))) short bf16x8;
typedef __attribute__((ext_vector_type(4))) float f32x4;

__device__ __forceinline__ float sigmoidf_(float x) {
  return 1.0f / (1.0f + __expf(-x));
}
__device__ __forceinline__ short f2bf(float x) {
  return (short)__bfloat16_as_ushort(__float2bfloat16(x));
}
__device__ __forceinline__ bf16x8 load_bf8(const float* p) {
  float4 a = *reinterpret_cast<const float4*>(p);
  float4 b = *reinterpret_cast<const float4*>(p + 4);
  bf16x8 r;
  r[0] = f2bf(a.x); r[1] = f2bf(a.y); r[2] = f2bf(a.z); r[3] = f2bf(a.w);
  r[4] = f2bf(b.x); r[5] = f2bf(b.y); r[6] = f2bf(b.z); r[7] = f2bf(b.w);
  return r;
}

// ---------------------------------------------------------------------------
// K_copy: pure flat copy, 4096 blocks x 256 thr x 26 quads = 27262976 quads.
// ---------------------------------------------------------------------------
__global__ __launch_bounds__(256) void cw_copy_kernel(
    const float4* __restrict__ S4, float4* __restrict__ O4)
{
  size_t i = (size_t)blockIdx.x * 256 + threadIdx.x;
  const size_t stride = (size_t)4096 * 256;
#pragma unroll 2
  for (int k = 0; k < 26; ++k) {
    O4[i] = S4[i];
    i += stride;
  }
}

// ---------------------------------------------------------------------------
// K_gate: 1024 blocks, 16 tokens each, 256 threads (4 waves).
// MFMA 16x16x32 bf16 layouts (m89-verified): A/B: row(col)=lane&15,
// k=(lane>>4)*8+e;  C/D: col=lane&15, row=(lane>>4)*4+reg.
// ---------------------------------------------------------------------------
__global__ __launch_bounds__(256) void cw_gate_kernel(
    const float* __restrict__ S, const float* __restrict__ H,
    const float* __restrict__ Wq, const float* __restrict__ Wg,
    const float* __restrict__ bg, const float* __restrict__ whs,
    const int* __restrict__ lip,
    float* __restrict__ outS, float* __restrict__ gate_out)
{
  __shared__ float gin[16][132];   // stride 132 -> 2-way bank alias (free)

  const int tid = threadIdx.x;
  const int li = *lip;
  const int start = (li > 8) ? (li - 8) : 0;
  const int ntags = li - start;
  const float tscale = (ntags > 0) ? (1.0f / (float)ntags) : 0.0f;
  const int trs = TAGOFF + start * 64;
  const int tok0 = blockIdx.x * 16;

  // ---- ph1: mean over past tags
#pragma unroll
  for (int r = 0; r < 4; ++r) {
    int o = r * 256 + tid;        // 16 tok x 64 d
    int tk = o >> 6, d = o & 63;
    const float* sp = S + (size_t)(tok0 + tk) * DSZ + trs + d;
    float acc = 0.f;
    for (int g = 0; g < ntags; ++g) acc += sp[g * 64];
    gin[tk][64 + d] = acc * tscale;
  }

  const int w = tid >> 6;
  const int l = tid & 63;
  const int l15 = l & 15, l4 = l >> 4;

  // ---- ph2: query = H * Wq^T; wave w owns q-tile w (16 q's)
  {
    const int q0 = w * 16;
    const float* ha = H + (size_t)(tok0 + l15) * DM + l4 * 8;
    const float* wq = Wq + (size_t)(q0 + l15) * DM + l4 * 8;
    f32x4 acc = {0.f, 0.f, 0.f, 0.f};
#pragma unroll 4
    for (int ks = 0; ks < 64; ++ks) {
      bf16x8 af = load_bf8(ha + ks * 32);
      bf16x8 bf = load_bf8(wq + ks * 32);
      acc = __builtin_amdgcn_mfma_f32_16x16x32_bf16(af, bf, acc, 0, 0, 0);
    }
#pragma unroll
    for (int i = 0; i < 4; ++i)
      gin[l4 * 4 + i][q0 + l15] = acc[i];
  }
  __syncthreads();

  // ---- ph3: gate = sigmoid(gin * Wg^T + bg); hub epilogue
  bf16x8 afr[4];
#pragma unroll
  for (int ks = 0; ks < 4; ++ks)
    afr[ks] = load_bf8(&gin[l15][ks * 32 + l4 * 8]);

  const float* wgb = Wg + (size_t)l15 * 128 + l4 * 8;
#pragma unroll
  for (int j = 0; j < 8; ++j) {
    const int ht = w * 8 + j;                  // h-tile 0..31
    const float* wgp = wgb + (size_t)ht * 16 * 128;
    f32x4 acc = {0.f, 0.f, 0.f, 0.f};
#pragma unroll
    for (int ks = 0; ks < 4; ++ks) {
      bf16x8 bf = load_bf8(wgp + ks * 32);
      acc = __builtin_amdgcn_mfma_f32_16x16x32_bf16(afr[ks], bf, acc, 0, 0, 0);
    }
    const int h = ht * 16 + l15;
    const float bgv = bg[h];
#pragma unroll
    for (int i = 0; i < 4; ++i) {
      int tok = tok0 + l4 * 4 + i;
      float g = sigmoidf_(acc[i] + bgv);
      gate_out[(size_t)tok * DHS + h] = g;
      size_t so = (size_t)tok * DSZ + HUBOFF + h;
      outS[so] = S[so] * g + whs[(size_t)tok * DHS + h];
    }
  }
}

// ---------------------------------------------------------------------------
// K_fixup: out[region] = S[region] + w for spoke/hub_priv/tag.
// 64 quads per token (32 spoke + 16 priv + 16 tag); 1024 blocks x 256 thr
// x 4 quads; each thread's 4 quads lie in one region (boundaries at 32,48).
// ---------------------------------------------------------------------------
__global__ __launch_bounds__(256) void cw_fixup_kernel(
    const float* __restrict__ S,
    const float* __restrict__ w_spoke, const float* __restrict__ w_hub_priv,
    const float* __restrict__ tg, const int* __restrict__ lip,
    float* __restrict__ outS)
{
  const int li = *lip;
  const unsigned sp0 = (unsigned)(li * 32);           // spoke quad col
  const unsigned hp0 = 768u + (unsigned)(li * 16);    // hub_priv quad col
  const unsigned tg0 = 1280u + (unsigned)(li * 16);   // tag quad col

  const float4* S4 = reinterpret_cast<const float4*>(S);
  const float4* SP4 = reinterpret_cast<const float4*>(w_spoke);
  const float4* HP4 = reinterpret_cast<const float4*>(w_hub_priv);
  const float4* TG4 = reinterpret_cast<const float4*>(tg);
  float4* O4 = reinterpret_cast<float4*>(outS);

  unsigned t = blockIdx.x * 256u + threadIdx.x;   // 0..262143
  unsigned tok = t >> 4;
  unsigned j0 = (t & 15u) * 4u;
  unsigned col;
  const float4* src;
  if (j0 < 32u)      { col = sp0 + j0;        src = SP4 + (size_t)tok * 32u + j0; }
  else if (j0 < 48u) { col = hp0 + (j0 - 32u); src = HP4 + (size_t)tok * 16u + (j0 - 32u); }
  else               { col = tg0 + (j0 - 48u); src = TG4 + (size_t)tok * 16u + (j0 - 48u); }

  size_t idx = (size_t)tok * 1664u + col;
#pragma unroll
  for (int k = 0; k < 4; ++k) {
    float4 s = S4[idx + k];
    float4 v = src[k];
    s.x += v.x; s.y += v.y; s.z += v.z; s.w += v.w;
    O4[idx + k] = s;
  }
}

extern "C" void kernel_launch(void* const* d_in, const int* in_sizes, int n_in,
                              void* d_out, int out_size, void* d_ws, size_t ws_size,
                              hipStream_t stream) {
  (void)in_sizes; (void)n_in; (void)out_size; (void)d_ws; (void)ws_size;
  const float* S            = (const float*)d_in[0];
  const float* H            = (const float*)d_in[1];
  const float* w_spoke      = (const float*)d_in[2];
  const float* w_hub_priv   = (const float*)d_in[3];
  const float* w_hub_shared = (const float*)d_in[4];
  const float* tg           = (const float*)d_in[5];
  const float* Wq           = (const float*)d_in[6];
  const float* Wg           = (const float*)d_in[7];
  const float* bg           = (const float*)d_in[8];
  const int*   lip          = (const int*)d_in[9];

  float* outS = (float*)d_out;
  float* gate_out = outS + (size_t)NTOK * DSZ;

  cw_copy_kernel<<<4096, 256, 0, stream>>>(
      reinterpret_cast<const float4*>(S), reinterpret_cast<float4*>(outS));
  cw_gate_kernel<<<1024, 256, 0, stream>>>(S, H, Wq, Wg, bg, w_hub_shared,
                                           lip, outS, gate_out);
  cw_fixup_kernel<<<1024, 256, 0, stream>>>(S, w_spoke, w_hub_priv, tg, lip, outS);
}